// Round 4
// baseline (437.923 us; speedup 1.0000x reference)
//
#include <hip/hip_runtime.h>
#include <hip/hip_bf16.h>

// Problem constants (B=4, S=4096, D=4096, r=4, COFF=2, HD=512)
#define D_DIM 4096
#define OD    1024          // COFF*HD combined projection width
#define M_TOT 16384         // B*S
#define N_TOT 2048          // 2*OD (kv/gate interleaved)
#define BM 128
#define BN 128
#define BK 64

#define GLOBAL_AS __attribute__((address_space(1)))
#define LDS_AS    __attribute__((address_space(3)))

typedef __attribute__((ext_vector_type(8))) short          bf16x8;
typedef __attribute__((ext_vector_type(8))) unsigned short u16x8;
typedef __attribute__((ext_vector_type(4))) float          f32x4;

__device__ __forceinline__ unsigned short f2bf(float f) {
    unsigned int u = __float_as_uint(f);
    u = (u + 0x7fffu + ((u >> 16) & 1u)) >> 16;
    return (unsigned short)u;
}

__device__ __forceinline__ float sigm(float x) {
    return 1.0f / (1.0f + __expf(-x));
}

__device__ __forceinline__ void gload16(const void* g, void* l) {
    // HBM -> LDS direct, 16 B/lane; LDS dest = wave-uniform base + lane*16 (linear)
    __builtin_amdgcn_global_load_lds((const GLOBAL_AS void*)g, (LDS_AS void*)l, 16, 0, 0);
}

// ---- prep: interleave wkv/wgate rows into combined bf16 weight [2048][4096]
__global__ void prep_weights(const float* __restrict__ wkv,
                             const float* __restrict__ wgate,
                             unsigned short* __restrict__ Wc) {
    int t  = blockIdx.x * 256 + threadIdx.x;   // 2048 * 512 threads
    int n  = t >> 9;                           // combined row: o = n>>1, gate = n&1
    int k8 = t & 511;                          // 8-element chunk in row
    const float* src = (n & 1) ? wgate : wkv;
    const float4* s4 = (const float4*)(src + (size_t)(n >> 1) * D_DIM + k8 * 8);
    float4 a = s4[0], b = s4[1];
    u16x8 o;
    o[0] = f2bf(a.x); o[1] = f2bf(a.y); o[2] = f2bf(a.z); o[3] = f2bf(a.w);
    o[4] = f2bf(b.x); o[5] = f2bf(b.y); o[6] = f2bf(b.z); o[7] = f2bf(b.w);
    *(u16x8*)(Wc + (size_t)n * D_DIM + k8 * 8) = o;
}

// ---- prep: x fp32 -> bf16
__global__ void prep_x(const float* __restrict__ x, unsigned short* __restrict__ xb) {
    size_t t = (size_t)blockIdx.x * 256 + threadIdx.x;  // 8,388,608 threads * 8 elems
    const float4* s = (const float4*)(x + t * 8);
    float4 a = s[0], b = s[1];
    u16x8 o;
    o[0] = f2bf(a.x); o[1] = f2bf(a.y); o[2] = f2bf(a.z); o[3] = f2bf(a.w);
    o[4] = f2bf(b.x); o[5] = f2bf(b.y); o[6] = f2bf(b.z); o[7] = f2bf(b.w);
    *(u16x8*)(xb + t * 8) = o;
}

// ---- prep: ape mean over the 4 window positions
__global__ void prep_ape(const float* __restrict__ ape, float* __restrict__ am) {
    int t = blockIdx.x * 256 + threadIdx.x;
    if (t < OD)
        am[t] = 0.25f * (ape[t] + ape[OD + t] + ape[2 * OD + t] + ape[3 * OD + t]);
}

// =====================================================================
// Main fused GEMM, pipelined: double-buffered LDS, stage tile t+1 BEFORE
// computing tile t, ONE __syncthreads per K-tile (its vmcnt(0) drain then
// waits on loads issued a full compute-phase earlier -> latency hidden).
// Pre-swizzled global source + XOR'd ds_read (verified 0-conflict, r3).
// XCD-swizzled block mapping: each XCD owns 2 n-tiles (B 2MB, L2-fits).
// =====================================================================
__global__ __launch_bounds__(256)
void gemm_fused_gl(const unsigned short* __restrict__ A,
                   const unsigned short* __restrict__ Wc,
                   const float* __restrict__ ape_mean,
                   float* __restrict__ out_pooled) {
    __shared__ __align__(16) unsigned short As[2][BM * BK];
    __shared__ __align__(16) unsigned short Bs[2][BN * BK];

    const int tid  = threadIdx.x;
    const int lane = tid & 63;
    const int wave = tid >> 6;           // 4 waves, 2x2 over the 128x128 tile
    const int wr   = wave >> 1;
    const int wc   = wave & 1;
    const int h    = lane & 15;
    const int q    = lane >> 4;

    // XCD-aware swizzle (2048 blocks, 16 n-tiles x 128 m-tiles):
    // XCD x (= bid%8) gets swz 256x..256x+255 -> n_tiles {2x,2x+1}.
    const int bid = blockIdx.x;
    const int swz = (bid & 7) * 256 + (bid >> 3);
    const int n0  = (swz >> 7) * BN;
    const int m0  = (swz & 127) * BM;

    // staging: wave w owns rows [w*32,(w+1)*32); issue i covers 8 rows.
    // SOURCE chunk pre-swizzled: sc8 = (l&7)^((l>>3)&7)  (row&7 == (l>>3)&7)
    const int srow = wave * 32 + (lane >> 3);
    const int sc8  = (lane & 7) ^ ((lane >> 3) & 7);
    const unsigned short* Ag = A  + (size_t)(m0 + srow) * D_DIM + sc8 * 8;
    const unsigned short* Bg = Wc + (size_t)(n0 + srow) * D_DIM + sc8 * 8;

#define STAGE(buf, kt)                                                          \
    do {                                                                        \
        _Pragma("unroll")                                                       \
        for (int i = 0; i < 4; ++i)                                             \
            gload16(Ag + (kt) + (size_t)(i * 8) * D_DIM,                        \
                    &As[buf][wave * 2048 + i * 512]);                           \
        _Pragma("unroll")                                                       \
        for (int i = 0; i < 4; ++i)                                             \
            gload16(Bg + (kt) + (size_t)(i * 8) * D_DIM,                        \
                    &Bs[buf][wave * 2048 + i * 512]);                           \
    } while (0)

#define COMPUTE(buf)                                                            \
    do {                                                                        \
        _Pragma("unroll")                                                       \
        for (int ks = 0; ks < 2; ++ks) {                                        \
            const int kb = ks * 32 + q * 8;                                     \
            bf16x8 af[4], bfr[4];                                               \
            _Pragma("unroll")                                                   \
            for (int am = 0; am < 4; ++am) {                                    \
                int row = wr * 64 + am * 16 + h;                                \
                af[am] = *(const bf16x8*)&As[buf][(row * BK + kb) ^             \
                                                  ((row & 7) << 3)];            \
            }                                                                   \
            _Pragma("unroll")                                                   \
            for (int bn = 0; bn < 4; ++bn) {                                    \
                int row = wc * 64 + bn * 16 + h;                                \
                bfr[bn] = *(const bf16x8*)&Bs[buf][(row * BK + kb) ^            \
                                                   ((row & 7) << 3)];           \
            }                                                                   \
            __builtin_amdgcn_s_setprio(1);                                      \
            _Pragma("unroll")                                                   \
            for (int am = 0; am < 4; ++am)                                      \
                _Pragma("unroll")                                               \
                for (int bn = 0; bn < 4; ++bn)                                  \
                    acc[am][bn] = __builtin_amdgcn_mfma_f32_16x16x32_bf16(      \
                        af[am], bfr[bn], acc[am][bn], 0, 0, 0);                 \
            __builtin_amdgcn_s_setprio(0);                                      \
        }                                                                       \
    } while (0)

    f32x4 acc[4][4];
    const f32x4 z = {0.f, 0.f, 0.f, 0.f};
#pragma unroll
    for (int i = 0; i < 4; ++i)
#pragma unroll
        for (int j = 0; j < 4; ++j) acc[i][j] = z;

    // prologue: stage tile 0, drain, barrier
    STAGE(0, 0);
    __syncthreads();

    // main loop: 2 K-tiles per trip (static buffer indices)
    for (int kt2 = 0; kt2 < D_DIM; kt2 += 2 * BK) {
        STAGE(1, kt2 + BK);                       // issue next-tile loads FIRST
        __builtin_amdgcn_sched_barrier(0);        // keep issues above compute
        COMPUTE(0);
        __syncthreads();                          // drain (waits on STAGE above)
        if (kt2 + 2 * BK < D_DIM) STAGE(0, kt2 + 2 * BK);
        __builtin_amdgcn_sched_barrier(0);
        COMPUTE(1);
        __syncthreads();
    }
#undef STAGE
#undef COMPUTE

    // Epilogue: even combined-cols = kv, odd = gate (adjacent lanes).
    // Lane's 4 acc regs = rows q*4..q*4+3 = one r=4 pooling window.
    const bool is_kv = ((h & 1) == 0);
#pragma unroll
    for (int am = 0; am < 4; ++am) {
        const int mbase = m0 + wr * 64 + am * 16 + q * 4;
        const int wglob = mbase >> 2;
#pragma unroll
        for (int bn = 0; bn < 4; ++bn) {
            f32x4 kv = acc[am][bn];
            float g0 = __shfl_xor(kv[0], 1);
            float g1 = __shfl_xor(kv[1], 1);
            float g2 = __shfl_xor(kv[2], 1);
            float g3 = __shfl_xor(kv[3], 1);
            if (is_kv) {
                float s = kv[0] * sigm(g0) + kv[1] * sigm(g1) +
                          kv[2] * sigm(g2) + kv[3] * sigm(g3);
                int n = n0 + wc * 64 + bn * 16 + h;   // even
                int o = n >> 1;
                out_pooled[(size_t)wglob * OD + o] = 0.25f * s + ape_mean[o];
            }
        }
    }
}

// ---- fallback (ws too small for xb): fp32 A + reg staging + XOR swizzle
__global__ __launch_bounds__(256)
void gemm_fused_f32(const float* __restrict__ Aptr,
                    const unsigned short* __restrict__ Wc,
                    const float* __restrict__ ape_mean,
                    float* __restrict__ out_pooled) {
    __shared__ __align__(16) unsigned short As[BM * BK];
    __shared__ __align__(16) unsigned short Bs[BN * BK];
    const int tid  = threadIdx.x;
    const int lane = tid & 63;
    const int wave = tid >> 6;
    const int wr   = wave >> 1;
    const int wc   = wave & 1;
    const int n0   = blockIdx.x * BN;
    const int m0   = blockIdx.y * BM;
    const int h    = lane & 15;
    const int q    = lane >> 4;

    f32x4 acc[4][4];
    const f32x4 z = {0.f, 0.f, 0.f, 0.f};
#pragma unroll
    for (int i = 0; i < 4; ++i)
#pragma unroll
        for (int j = 0; j < 4; ++j) acc[i][j] = z;

    for (int kt = 0; kt < D_DIM; kt += BK) {
#pragma unroll
        for (int i = 0; i < 4; ++i) {
            int chunk = tid + i * 256;
            int row = chunk >> 3, c8 = chunk & 7;
            int dst = (row * BK + c8 * 8) ^ ((row & 7) << 3);
            const float4* s = (const float4*)(Aptr + (size_t)(m0 + row) * D_DIM + kt + c8 * 8);
            float4 a = s[0], b = s[1];
            u16x8 o;
            o[0] = f2bf(a.x); o[1] = f2bf(a.y); o[2] = f2bf(a.z); o[3] = f2bf(a.w);
            o[4] = f2bf(b.x); o[5] = f2bf(b.y); o[6] = f2bf(b.z); o[7] = f2bf(b.w);
            *(u16x8*)&As[dst] = o;
        }
#pragma unroll
        for (int i = 0; i < 4; ++i) {
            int chunk = tid + i * 256;
            int row = chunk >> 3, c8 = chunk & 7;
            int dst = (row * BK + c8 * 8) ^ ((row & 7) << 3);
            *(u16x8*)&Bs[dst] =
                *(const u16x8*)(Wc + (size_t)(n0 + row) * D_DIM + kt + c8 * 8);
        }
        __syncthreads();
#pragma unroll
        for (int ks = 0; ks < 2; ++ks) {
            const int kb = ks * 32 + q * 8;
            bf16x8 af[4], bfr[4];
#pragma unroll
            for (int am = 0; am < 4; ++am) {
                int row = wr * 64 + am * 16 + h;
                af[am] = *(const bf16x8*)&As[(row * BK + kb) ^ ((row & 7) << 3)];
            }
#pragma unroll
            for (int bn = 0; bn < 4; ++bn) {
                int row = wc * 64 + bn * 16 + h;
                bfr[bn] = *(const bf16x8*)&Bs[(row * BK + kb) ^ ((row & 7) << 3)];
            }
#pragma unroll
            for (int am = 0; am < 4; ++am)
#pragma unroll
                for (int bn = 0; bn < 4; ++bn)
                    acc[am][bn] = __builtin_amdgcn_mfma_f32_16x16x32_bf16(
                        af[am], bfr[bn], acc[am][bn], 0, 0, 0);
        }
        __syncthreads();
    }
    const bool is_kv = ((h & 1) == 0);
#pragma unroll
    for (int am = 0; am < 4; ++am) {
        const int mbase = m0 + wr * 64 + am * 16 + q * 4;
        const int wglob = mbase >> 2;
#pragma unroll
        for (int bn = 0; bn < 4; ++bn) {
            f32x4 kv = acc[am][bn];
            float g0 = __shfl_xor(kv[0], 1);
            float g1 = __shfl_xor(kv[1], 1);
            float g2 = __shfl_xor(kv[2], 1);
            float g3 = __shfl_xor(kv[3], 1);
            if (is_kv) {
                float s = kv[0] * sigm(g0) + kv[1] * sigm(g1) +
                          kv[2] * sigm(g2) + kv[3] * sigm(g3);
                int n = n0 + wc * 64 + bn * 16 + h;
                int o = n >> 1;
                out_pooled[(size_t)wglob * OD + o] = 0.25f * s + ape_mean[o];
            }
        }
    }
}

// ---- in-place RMSNorm over head_dim=512 per token (8192 tokens)
__global__ void rmsnorm_inplace(float* __restrict__ out, const float* __restrict__ nw) {
    int token = blockIdx.x * 4 + (threadIdx.x >> 6);   // one wave per token
    int lane  = threadIdx.x & 63;
    float4* p = (float4*)(out + (size_t)token * 512);
    float4 v0 = p[lane * 2], v1 = p[lane * 2 + 1];
    float ss = v0.x * v0.x + v0.y * v0.y + v0.z * v0.z + v0.w * v0.w +
               v1.x * v1.x + v1.y * v1.y + v1.z * v1.z + v1.w * v1.w;
#pragma unroll
    for (int off = 32; off > 0; off >>= 1) ss += __shfl_xor(ss, off);
    float rs = rsqrtf(ss * (1.0f / 512.0f) + 1e-6f);
    const float4* w4 = (const float4*)nw;
    float4 w0 = w4[lane * 2], w1 = w4[lane * 2 + 1];
    float4 r0, r1;
    r0.x = v0.x * rs * w0.x; r0.y = v0.y * rs * w0.y;
    r0.z = v0.z * rs * w0.z; r0.w = v0.w * rs * w0.w;
    r1.x = v1.x * rs * w1.x; r1.y = v1.y * rs * w1.y;
    r1.z = v1.z * rs * w1.z; r1.w = v1.w * rs * w1.w;
    p[lane * 2]     = r0;
    p[lane * 2 + 1] = r1;
}

extern "C" void kernel_launch(void* const* d_in, const int* in_sizes, int n_in,
                              void* d_out, int out_size, void* d_ws, size_t ws_size,
                              hipStream_t stream) {
    const float* x     = (const float*)d_in[0];
    const float* wkv   = (const float*)d_in[1];
    const float* wgate = (const float*)d_in[2];
    const float* ape   = (const float*)d_in[3];
    const float* normw = (const float*)d_in[4];
    float* out = (float*)d_out;

    unsigned short* Wc  = (unsigned short*)d_ws;
    float* ape_mean     = (float*)((char*)d_ws + (size_t)16 * 1024 * 1024);
    unsigned short* xb  = (unsigned short*)((char*)d_ws + (size_t)16 * 1024 * 1024 + 65536);
    const size_t need_xb = (size_t)16 * 1024 * 1024 + 65536 + (size_t)M_TOT * D_DIM * 2;
    const bool use_xb = (ws_size >= need_xb);

    prep_weights<<<4096, 256, 0, stream>>>(wkv, wgate, Wc);
    prep_ape<<<4, 256, 0, stream>>>(ape, ape_mean);

    if (use_xb) {
        prep_x<<<32768, 256, 0, stream>>>(x, xb);
        gemm_fused_gl<<<(N_TOT / BN) * (M_TOT / BM), 256, 0, stream>>>(
            xb, Wc, ape_mean, out);
    } else {
        gemm_fused_f32<<<dim3(N_TOT / BN, M_TOT / BM), 256, 0, stream>>>(
            x, Wc, ape_mean, out);
    }

    rmsnorm_inplace<<<2048, 256, 0, stream>>>(out, normw);
}

// Round 5
// 330.755 us; speedup vs baseline: 1.3240x; 1.3240x over previous
//
#include <hip/hip_runtime.h>
#include <hip/hip_bf16.h>

// Problem constants (B=4, S=4096, D=4096, r=4, COFF=2, HD=512)
#define D_DIM 4096
#define OD    1024          // COFF*HD combined projection width
#define M_TOT 16384         // B*S
#define N_TOT 2048          // 2*OD (kv/gate interleaved)
#define BM 256
#define BN 256
#define BK 64

#define GLOBAL_AS __attribute__((address_space(1)))
#define LDS_AS    __attribute__((address_space(3)))

typedef __attribute__((ext_vector_type(8))) short          bf16x8;
typedef __attribute__((ext_vector_type(8))) unsigned short u16x8;
typedef __attribute__((ext_vector_type(4))) float          f32x4;

__device__ __forceinline__ unsigned short f2bf(float f) {
    unsigned int u = __float_as_uint(f);
    u = (u + 0x7fffu + ((u >> 16) & 1u)) >> 16;
    return (unsigned short)u;
}

__device__ __forceinline__ float sigm(float x) {
    return 1.0f / (1.0f + __expf(-x));
}

__device__ __forceinline__ void gload16(const void* g, void* l) {
    __builtin_amdgcn_global_load_lds((const GLOBAL_AS void*)g, (LDS_AS void*)l, 16, 0, 0);
}

// ---- prep: interleave wkv/wgate rows into combined bf16 weight [2048][4096]
__global__ void prep_weights(const float* __restrict__ wkv,
                             const float* __restrict__ wgate,
                             unsigned short* __restrict__ Wc) {
    int t  = blockIdx.x * 256 + threadIdx.x;
    int n  = t >> 9;
    int k8 = t & 511;
    const float* src = (n & 1) ? wgate : wkv;
    const float4* s4 = (const float4*)(src + (size_t)(n >> 1) * D_DIM + k8 * 8);
    float4 a = s4[0], b = s4[1];
    u16x8 o;
    o[0] = f2bf(a.x); o[1] = f2bf(a.y); o[2] = f2bf(a.z); o[3] = f2bf(a.w);
    o[4] = f2bf(b.x); o[5] = f2bf(b.y); o[6] = f2bf(b.z); o[7] = f2bf(b.w);
    *(u16x8*)(Wc + (size_t)n * D_DIM + k8 * 8) = o;
}

// ---- prep: x fp32 -> bf16
__global__ void prep_x(const float* __restrict__ x, unsigned short* __restrict__ xb) {
    size_t t = (size_t)blockIdx.x * 256 + threadIdx.x;
    const float4* s = (const float4*)(x + t * 8);
    float4 a = s[0], b = s[1];
    u16x8 o;
    o[0] = f2bf(a.x); o[1] = f2bf(a.y); o[2] = f2bf(a.z); o[3] = f2bf(a.w);
    o[4] = f2bf(b.x); o[5] = f2bf(b.y); o[6] = f2bf(b.z); o[7] = f2bf(b.w);
    *(u16x8*)(xb + t * 8) = o;
}

// ---- prep: ape mean over the 4 window positions
__global__ void prep_ape(const float* __restrict__ ape, float* __restrict__ am) {
    int t = blockIdx.x * 256 + threadIdx.x;
    if (t < OD)
        am[t] = 0.25f * (ape[t] + ape[OD + t] + ape[2 * OD + t] + ape[3 * OD + t]);
}

// =====================================================================
// 256x256 / BK=64 / 8-wave / 8-phase GEMM (T2+T3+T4+T5).
// Per iteration: 2 K-tiles (buf0, buf1). Each phase: 12 ds_read_b128
// (one acc quadrant) + 1 quarter-unit stage (2 gload_lds) + barrier +
// 16 MFMA + barrier. vmcnt(4) ONLY at phases 4 and 8 (2 units stay in
// flight). Stage targets are units fully consumed in earlier phases:
//   quadrant order (qa,qb): (0,0),(1,0),(0,1),(1,1)
//   A quarter-units: A0={rows 0-63,128-191} (consumed ph1,3),
//                    A1={64-127,192-255}    (consumed ph2,4)
//   B stripe-units:  B0={n 0-31,64-95,128-159,192-223} (consumed ph1,2),
//                    B1=+32 offset                      (consumed ph3,4)
// Epilogue: gate via shfl_xor(1), r=4 window-mean in-register, +ape_mean.
// =====================================================================
extern __shared__ __align__(16) unsigned short smem_u16[];

__global__ __launch_bounds__(512)
void gemm_fused_8ph(const unsigned short* __restrict__ A,
                    const unsigned short* __restrict__ Wc,
                    const float* __restrict__ ape_mean,
                    float* __restrict__ out_pooled) {
    unsigned short* Asb[2] = {smem_u16,             smem_u16 + BM * BK};
    unsigned short* Bsb[2] = {smem_u16 + 2 * BM * BK, smem_u16 + 3 * BM * BK};

    const int tid  = threadIdx.x;
    const int lane = tid & 63;
    const int wave = tid >> 6;          // 8 waves: wm = wave>>2 (2), wn = wave&3 (4)
    const int wm   = wave >> 2;
    const int wn   = wave & 3;
    const int h    = lane & 15;
    const int q    = lane >> 4;

    // XCD partition by m: xcd = bid&7 owns m-tiles [xcd*8, xcd*8+8), all 8 n-tiles.
    const int bid = blockIdx.x;
    const int j   = bid >> 3;
    const int m0  = ((bid & 7) * 8 + (j >> 3)) * BM;
    const int n0  = (j & 7) * BN;

    // staging: pre-swizzled source chunk (rule 21 both-sides; verified r3)
    const int sc8 = (lane & 7) ^ ((lane >> 3) & 7);
    const unsigned short* Ag = A  + (size_t)(m0 + wave * 8 + (lane >> 3)) * D_DIM + sc8 * 8;
    const unsigned short* Bg = Wc + (size_t)(n0 + (wave & 3) * 8 + (lane >> 3)) * D_DIM + sc8 * 8;
    const int bstripe = wave >> 2;      // waves 0-3: stripes {0,2}; 4-7: {1,3}

#define STAGE_A(buf, half, kofs)                                                   \
    do {                                                                           \
        gload16(Ag + (size_t)((half) * 64) * D_DIM + (kofs),                       \
                Asb[buf] + ((half) * 64 + wave * 8) * BK);                         \
        gload16(Ag + (size_t)((half) * 64 + 128) * D_DIM + (kofs),                 \
                Asb[buf] + ((half) * 64 + 128 + wave * 8) * BK);                   \
    } while (0)

#define STAGE_B(buf, qb, kofs)                                                     \
    do {                                                                           \
        const int r0_ = (qb) * 32 + bstripe * 64;                                  \
        const int r1_ = (qb) * 32 + (2 + bstripe) * 64;                            \
        gload16(Bg + (size_t)r0_ * D_DIM + (kofs),                                 \
                Bsb[buf] + (r0_ + (wave & 3) * 8) * BK);                           \
        gload16(Bg + (size_t)r1_ * D_DIM + (kofs),                                 \
                Bsb[buf] + (r1_ + (wave & 3) * 8) * BK);                           \
    } while (0)

#define PHASE(buf, qa, qb, STAGECODE, VM)                                          \
    do {                                                                           \
        bf16x8 av[4][2], bv[2][2];                                                 \
        _Pragma("unroll")                                                          \
        for (int mi = 0; mi < 4; ++mi) {                                           \
            const int row = wm * 128 + ((qa) * 4 + mi) * 16 + h;                   \
            _Pragma("unroll")                                                      \
            for (int ks = 0; ks < 2; ++ks)                                         \
                av[mi][ks] = *(const bf16x8*)&Asb[buf][(row * BK + ks * 32 +       \
                             q * 8) ^ ((row & 7) << 3)];                           \
        }                                                                          \
        _Pragma("unroll")                                                          \
        for (int ni = 0; ni < 2; ++ni) {                                           \
            const int rw = wn * 64 + ((qb) * 2 + ni) * 16 + h;                     \
            _Pragma("unroll")                                                      \
            for (int ks = 0; ks < 2; ++ks)                                         \
                bv[ni][ks] = *(const bf16x8*)&Bsb[buf][(rw * BK + ks * 32 +        \
                             q * 8) ^ ((rw & 7) << 3)];                            \
        }                                                                          \
        STAGECODE;                                                                 \
        if (VM) asm volatile("s_waitcnt vmcnt(4)" ::: "memory");                   \
        __builtin_amdgcn_s_barrier();                                              \
        __builtin_amdgcn_s_setprio(1);                                             \
        _Pragma("unroll")                                                          \
        for (int mi = 0; mi < 4; ++mi)                                             \
            _Pragma("unroll")                                                      \
            for (int ni = 0; ni < 2; ++ni)                                         \
                _Pragma("unroll")                                                  \
                for (int ks = 0; ks < 2; ++ks)                                     \
                    acc[(qa) * 4 + mi][(qb) * 2 + ni] =                            \
                        __builtin_amdgcn_mfma_f32_16x16x32_bf16(                   \
                            av[mi][ks], bv[ni][ks],                                \
                            acc[(qa) * 4 + mi][(qb) * 2 + ni], 0, 0, 0);           \
        __builtin_amdgcn_s_setprio(0);                                             \
        __builtin_amdgcn_s_barrier();                                              \
    } while (0)

    f32x4 acc[8][4];
    const f32x4 z = {0.f, 0.f, 0.f, 0.f};
#pragma unroll
    for (int i = 0; i < 8; ++i)
#pragma unroll
        for (int jj = 0; jj < 4; ++jj) acc[i][jj] = z;

    // prologue: T0 full (buf0), then T1's B0,A0 (buf1) -> steady-state entry
    STAGE_A(0, 0, 0); STAGE_A(0, 1, 0); STAGE_B(0, 0, 0); STAGE_B(0, 1, 0);
    STAGE_B(1, 0, 64); STAGE_A(1, 0, 64);
    asm volatile("s_waitcnt vmcnt(4)" ::: "memory");   // T0's 8 loads landed
    __builtin_amdgcn_s_barrier();

    for (int kt2 = 0; kt2 < D_DIM; kt2 += 2 * BK) {
        const int kb1 = kt2 + BK;                // this iter's tile b (<= 4032)
        const int kna = (kt2 + 2 * BK) & 4095;   // next tile a (wraps last trip)
        const int knb = (kt2 + 3 * BK) & 4095;   // next tile b
        PHASE(0, 0, 0, STAGE_A(1, 1, kb1), 0);   // ph1: A1 of Tb -> buf1
        PHASE(0, 1, 0, STAGE_B(1, 1, kb1), 0);   // ph2: B1 of Tb -> buf1
        PHASE(0, 0, 1, STAGE_B(0, 0, kna), 0);   // ph3: B0 of Tna -> buf0
        PHASE(0, 1, 1, STAGE_A(0, 0, kna), 1);   // ph4: A0 of Tna -> buf0 + vmcnt
        PHASE(1, 0, 0, STAGE_A(0, 1, kna), 0);   // ph5: A1 of Tna -> buf0
        PHASE(1, 1, 0, STAGE_B(0, 1, kna), 0);   // ph6: B1 of Tna -> buf0
        PHASE(1, 0, 1, STAGE_B(1, 0, knb), 0);   // ph7: B0 of Tnb -> buf1
        PHASE(1, 1, 1, STAGE_A(1, 0, knb), 1);   // ph8: A0 of Tnb -> buf1 + vmcnt
    }
#undef STAGE_A
#undef STAGE_B
#undef PHASE

    // Epilogue: even combined-cols = kv, odd = gate (adjacent lanes).
    // Lane's 4 acc regs = rows q*4..q*4+3 = one r=4 pooling window.
    const bool is_kv = ((h & 1) == 0);
#pragma unroll
    for (int mi = 0; mi < 8; ++mi) {
        const int mbase = m0 + wm * 128 + mi * 16 + q * 4;
        const int wglob = mbase >> 2;
#pragma unroll
        for (int ni = 0; ni < 4; ++ni) {
            f32x4 kv = acc[mi][ni];
            float g0 = __shfl_xor(kv[0], 1);
            float g1 = __shfl_xor(kv[1], 1);
            float g2 = __shfl_xor(kv[2], 1);
            float g3 = __shfl_xor(kv[3], 1);
            if (is_kv) {
                float s = kv[0] * sigm(g0) + kv[1] * sigm(g1) +
                          kv[2] * sigm(g2) + kv[3] * sigm(g3);
                int n = n0 + wn * 64 + ni * 16 + h;   // even
                int o = n >> 1;
                out_pooled[(size_t)wglob * OD + o] = 0.25f * s + ape_mean[o];
            }
        }
    }
}

// ---- fallback (ws too small for xb): fp32 A + reg staging + XOR swizzle (r3)
__global__ __launch_bounds__(256)
void gemm_fused_f32(const float* __restrict__ Aptr,
                    const unsigned short* __restrict__ Wc,
                    const float* __restrict__ ape_mean,
                    float* __restrict__ out_pooled) {
    __shared__ __align__(16) unsigned short As[128 * BK];
    __shared__ __align__(16) unsigned short Bs[128 * BK];
    const int tid  = threadIdx.x;
    const int lane = tid & 63;
    const int wave = tid >> 6;
    const int wr   = wave >> 1;
    const int wc   = wave & 1;
    const int n0   = blockIdx.x * 128;
    const int m0   = blockIdx.y * 128;
    const int h    = lane & 15;
    const int q    = lane >> 4;

    f32x4 acc[4][4];
    const f32x4 z = {0.f, 0.f, 0.f, 0.f};
#pragma unroll
    for (int i = 0; i < 4; ++i)
#pragma unroll
        for (int jj = 0; jj < 4; ++jj) acc[i][jj] = z;

    for (int kt = 0; kt < D_DIM; kt += BK) {
#pragma unroll
        for (int i = 0; i < 4; ++i) {
            int chunk = tid + i * 256;
            int row = chunk >> 3, c8 = chunk & 7;
            int dst = (row * BK + c8 * 8) ^ ((row & 7) << 3);
            const float4* s = (const float4*)(Aptr + (size_t)(m0 + row) * D_DIM + kt + c8 * 8);
            float4 a = s[0], b = s[1];
            u16x8 o;
            o[0] = f2bf(a.x); o[1] = f2bf(a.y); o[2] = f2bf(a.z); o[3] = f2bf(a.w);
            o[4] = f2bf(b.x); o[5] = f2bf(b.y); o[6] = f2bf(b.z); o[7] = f2bf(b.w);
            *(u16x8*)&As[dst] = o;
        }
#pragma unroll
        for (int i = 0; i < 4; ++i) {
            int chunk = tid + i * 256;
            int row = chunk >> 3, c8 = chunk & 7;
            int dst = (row * BK + c8 * 8) ^ ((row & 7) << 3);
            *(u16x8*)&Bs[dst] =
                *(const u16x8*)(Wc + (size_t)(n0 + row) * D_DIM + kt + c8 * 8);
        }
        __syncthreads();
#pragma unroll
        for (int ks = 0; ks < 2; ++ks) {
            const int kb = ks * 32 + q * 8;
            bf16x8 af[4], bfr[4];
#pragma unroll
            for (int am = 0; am < 4; ++am) {
                int row = wr * 64 + am * 16 + h;
                af[am] = *(const bf16x8*)&As[(row * BK + kb) ^ ((row & 7) << 3)];
            }
#pragma unroll
            for (int bn = 0; bn < 4; ++bn) {
                int row = wc * 64 + bn * 16 + h;
                bfr[bn] = *(const bf16x8*)&Bs[(row * BK + kb) ^ ((row & 7) << 3)];
            }
#pragma unroll
            for (int am = 0; am < 4; ++am)
#pragma unroll
                for (int bn = 0; bn < 4; ++bn)
                    acc[am][bn] = __builtin_amdgcn_mfma_f32_16x16x32_bf16(
                        af[am], bfr[bn], acc[am][bn], 0, 0, 0);
        }
        __syncthreads();
    }
    const bool is_kv = ((h & 1) == 0);
#pragma unroll
    for (int am = 0; am < 4; ++am) {
        const int mbase = m0 + wr * 64 + am * 16 + q * 4;
        const int wglob = mbase >> 2;
#pragma unroll
        for (int bn = 0; bn < 4; ++bn) {
            f32x4 kv = acc[am][bn];
            float g0 = __shfl_xor(kv[0], 1);
            float g1 = __shfl_xor(kv[1], 1);
            float g2 = __shfl_xor(kv[2], 1);
            float g3 = __shfl_xor(kv[3], 1);
            if (is_kv) {
                float s = kv[0] * sigm(g0) + kv[1] * sigm(g1) +
                          kv[2] * sigm(g2) + kv[3] * sigm(g3);
                int n = n0 + wc * 64 + bn * 16 + h;
                int o = n >> 1;
                out_pooled[(size_t)wglob * OD + o] = 0.25f * s + ape_mean[o];
            }
        }
    }
}

// ---- in-place RMSNorm over head_dim=512 per token (8192 tokens)
__global__ void rmsnorm_inplace(float* __restrict__ out, const float* __restrict__ nw) {
    int token = blockIdx.x * 4 + (threadIdx.x >> 6);
    int lane  = threadIdx.x & 63;
    float4* p = (float4*)(out + (size_t)token * 512);
    float4 v0 = p[lane * 2], v1 = p[lane * 2 + 1];
    float ss = v0.x * v0.x + v0.y * v0.y + v0.z * v0.z + v0.w * v0.w +
               v1.x * v1.x + v1.y * v1.y + v1.z * v1.z + v1.w * v1.w;
#pragma unroll
    for (int off = 32; off > 0; off >>= 1) ss += __shfl_xor(ss, off);
    float rs = rsqrtf(ss * (1.0f / 512.0f) + 1e-6f);
    const float4* w4 = (const float4*)nw;
    float4 w0 = w4[lane * 2], w1 = w4[lane * 2 + 1];
    float4 r0, r1;
    r0.x = v0.x * rs * w0.x; r0.y = v0.y * rs * w0.y;
    r0.z = v0.z * rs * w0.z; r0.w = v0.w * rs * w0.w;
    r1.x = v1.x * rs * w1.x; r1.y = v1.y * rs * w1.y;
    r1.z = v1.z * rs * w1.z; r1.w = v1.w * rs * w1.w;
    p[lane * 2]     = r0;
    p[lane * 2 + 1] = r1;
}

extern "C" void kernel_launch(void* const* d_in, const int* in_sizes, int n_in,
                              void* d_out, int out_size, void* d_ws, size_t ws_size,
                              hipStream_t stream) {
    const float* x     = (const float*)d_in[0];
    const float* wkv   = (const float*)d_in[1];
    const float* wgate = (const float*)d_in[2];
    const float* ape   = (const float*)d_in[3];
    const float* normw = (const float*)d_in[4];
    float* out = (float*)d_out;

    unsigned short* Wc  = (unsigned short*)d_ws;
    float* ape_mean     = (float*)((char*)d_ws + (size_t)16 * 1024 * 1024);
    unsigned short* xb  = (unsigned short*)((char*)d_ws + (size_t)16 * 1024 * 1024 + 65536);
    const size_t need_xb = (size_t)16 * 1024 * 1024 + 65536 + (size_t)M_TOT * D_DIM * 2;
    const bool use_xb = (ws_size >= need_xb);

    prep_weights<<<4096, 256, 0, stream>>>(wkv, wgate, Wc);
    prep_ape<<<4, 256, 0, stream>>>(ape, ape_mean);

    if (use_xb) {
        prep_x<<<32768, 256, 0, stream>>>(x, xb);
        (void)hipFuncSetAttribute(
            reinterpret_cast<const void*>(&gemm_fused_8ph),
            hipFuncAttributeMaxDynamicSharedMemorySize, 131072);
        gemm_fused_8ph<<<(M_TOT / BM) * (N_TOT / BN), 512, 131072, stream>>>(
            xb, Wc, ape_mean, out);
    } else {
        gemm_fused_f32<<<dim3(N_TOT / 128, M_TOT / 128), 256, 0, stream>>>(
            x, Wc, ape_mean, out);
    }

    rmsnorm_inplace<<<2048, 256, 0, stream>>>(out, normw);
}